// Round 14
// baseline (231.132 us; speedup 1.0000x reference)
//
#include <hip/hip_runtime.h>

// LSTM B=8192, T=512, I=1, H=32; out[b] = h_T . W_lin + b_lin.  All I/O f32.
//
// MFMA formulation, 4 waves per 16-batch group (512 blocks x 256 threads),
// custom tiles (zero MFMA duplication), 2 hiddens/lane, fused-rcp acts with
// PAIRED rcp (R13 green). R14 delta: x stored in LDS as [b][t] (stride 516
// floats -> bank 4c+t, 2-way aliasing = free) and read as ONE ds_read_b128
// per 4 steps (next quad prefetched 3 steps early) instead of 4 stride-17
// b32 reads + address math.
//
// Wave wv owns hiddens [8wv, 8wv+8). Lane (quad,col) owns j0 = 8wv+2quad+0
// and j1 = j0+1 of batch col. Custom A-tile tau: row m = 4a+r holds W_hh
// gate-row [type r][hidden 8wv+2a+tau] (row-permuting A permutes D rows
// identically), so acc[tau] slots 0..3 = {i,f,g,o} of hidden j0+tau.
// 2 MFMAs/wave-step, no duplication. 2048 waves = 2/SIMD.
//
// Activations (12 trans/lane-step = 10 exp2 + 2 paired rcp):
//   e* = 2^(-z*'), a* = 1+e*;  D = aF*aI*aG per hidden
//   paired: r = rcp(D0*D1); 1/D0 = r*D1, 1/D1 = r*D0
//   c' = (c*aI*aG + (1-eG)*aF) / D
//   eC = 2^(-2*L2E*c'); H = aO*(1+eC) paired-rcp; h = (1-eC)/H
// Pre-acts pre-scaled by L2E (2*L2E for the g gate).
// NOTE: packed f32x2 (v_pk_*) activation math failed the harness post-timing
// determinism check in R12 — do not reintroduce.

#define L2E 1.4426950408889634f

typedef _Float16 f16x8 __attribute__((ext_vector_type(8)));
typedef float    f32x4 __attribute__((ext_vector_type(4)));

__global__ __launch_bounds__(256, 4) void lstm_ct4x(
    const float* __restrict__ x,      // [B*512]
    const float* __restrict__ W_ih,   // [128]
    const float* __restrict__ W_hh,   // [128*32]
    const float* __restrict__ b_ih,   // [128]
    const float* __restrict__ b_hh,   // [128]
    const float* __restrict__ W_lin,  // [32]
    const float* __restrict__ b_lin,  // [1]
    float* __restrict__ out)          // [B]
{
    __shared__ float xs[16 * 516];                        // x [b][t], b-stride 516
    __shared__ __align__(16) unsigned int hb[2][16 * 20]; // h half2 buffers, col-stride 20 uints
    __shared__ float ps[64];                              // epilogue partials

    const int tid  = threadIdx.x;
    const int wv   = tid >> 6;         // 0..3: owns hiddens [8wv, 8wv+8)
    const int lane = tid & 63;
    const int col  = lane & 15;        // batch within group
    const int quad = lane >> 4;        // 0..3
    const int base = blockIdx.x * 16;  // global batch base

    // ---- stage x[base..base+15][0..511] into LDS [b][t] (contiguous b128) ----
    {
        const float4* xg = (const float4*)(x + (size_t)base * 512);
        #pragma unroll
        for (int it = 0; it < 8; ++it) {
            int idx = it * 256 + tid;          // 0..2047 float4s
            float4 v = xg[idx];
            int b  = idx >> 7;                 // batch 0..15
            int t0 = (idx & 127) * 4;
            *(float4*)&xs[b * 516 + t0] = v;
        }
    }

    // ---- custom A-tiles: tile tau row m=4a+rt -> W_hh[32*rt + 8wv+2a+tau] ----
    f16x8 wA[2];
    #pragma unroll
    for (int tau = 0; tau < 2; ++tau) {
        const int rt = col & 3;                           // gate type of row col
        const float s = (rt == 2) ? (2.0f * L2E) : L2E;
        const int grow = 32 * rt + 8 * wv + 2 * (col >> 2) + tau;
        #pragma unroll
        for (int j = 0; j < 8; ++j)
            wA[tau][j] = (_Float16)(W_hh[grow * 32 + quad * 8 + j] * s);
    }
    // C-init constants: acc[tau] slot r = gate type r of hidden j0+tau
    const int j0 = 8 * wv + 2 * quad;                     // first owned hidden
    float wih[2][4], bia[2][4];
    #pragma unroll
    for (int tau = 0; tau < 2; ++tau)
        #pragma unroll
        for (int r = 0; r < 4; ++r) {
            const float s = (r == 2) ? (2.0f * L2E) : L2E;
            const int g = 32 * r + j0 + tau;
            wih[tau][r] = W_ih[g] * s;
            bia[tau][r] = (b_ih[g] + b_hh[g]) * s;
        }
    const float wl0 = W_lin[j0], wl1 = W_lin[j0 + 1];

    __syncthreads();

    const float* xrow = &xs[col * 516];
    float c0 = 0.0f, c1 = 0.0f, h0 = 0.0f, h1 = 0.0f;
    f16x8 bfrag = {};                  // h = 0
    float4 xcur = *(const float4*)xrow;                   // x[t=0..3]
    f32x4 cq[2];
    {
        float xt = xcur.x;             // t = 0
        #pragma unroll
        for (int tau = 0; tau < 2; ++tau)
            #pragma unroll
            for (int r = 0; r < 4; ++r)
                cq[tau][r] = fmaf(xt, wih[tau][r], bia[tau][r]);
    }

    const int wr = col * 20 + 4 * wv + quad;   // h-pair write index (= j0/2 slot)

    for (int t4 = 0; t4 < 128; ++t4) {
        // prefetch next 4 x values (needed first at u=3's C-init — ~3 steps away)
        float4 xnxt = *(const float4*)&xrow[(4 * t4 + 4) & 511];

        #pragma unroll
        for (int u = 0; u < 4; ++u) {
            unsigned int* buf = hb[u & 1];     // parity = t&1 (4 | even)

            f32x4 a0 = __builtin_amdgcn_mfma_f32_16x16x32_f16(wA[0], bfrag, cq[0], 0, 0, 0);
            f32x4 a1 = __builtin_amdgcn_mfma_f32_16x16x32_f16(wA[1], bfrag, cq[1], 0, 0, 0);

            // fused activations, hidden j0 (a0) and j0+1 (a1); rcps PAIRED
            float ei0 = __builtin_amdgcn_exp2f(-a0[0]);
            float ef0 = __builtin_amdgcn_exp2f(-a0[1]);
            float eg0 = __builtin_amdgcn_exp2f(-a0[2]);
            float eo0 = __builtin_amdgcn_exp2f(-a0[3]);
            float ei1 = __builtin_amdgcn_exp2f(-a1[0]);
            float ef1 = __builtin_amdgcn_exp2f(-a1[1]);
            float eg1 = __builtin_amdgcn_exp2f(-a1[2]);
            float eo1 = __builtin_amdgcn_exp2f(-a1[3]);
            float aI0 = 1.0f + ei0, aF0 = 1.0f + ef0, aG0 = 1.0f + eg0, aO0 = 1.0f + eo0;
            float aI1 = 1.0f + ei1, aF1 = 1.0f + ef1, aG1 = 1.0f + eg1, aO1 = 1.0f + eo1;
            float tIG0 = aI0 * aG0, tIG1 = aI1 * aG1;
            float num0 = fmaf(c0, tIG0, (1.0f - eg0) * aF0);
            float num1 = fmaf(c1, tIG1, (1.0f - eg1) * aF1);
            float D0 = aF0 * tIG0, D1 = aF1 * tIG1;
            float rD = __builtin_amdgcn_rcpf(D0 * D1);        // paired rcp #1
            c0 = num0 * (rD * D1);
            c1 = num1 * (rD * D0);
            float ec0 = __builtin_amdgcn_exp2f(c0 * (-2.0f * L2E));
            float ec1 = __builtin_amdgcn_exp2f(c1 * (-2.0f * L2E));
            float H0 = aO0 * (1.0f + ec0), H1 = aO1 * (1.0f + ec1);
            float rH = __builtin_amdgcn_rcpf(H0 * H1);        // paired rcp #2
            h0 = (1.0f - ec0) * (rH * H1);
            h1 = (1.0f - ec1) * (rH * H0);

            // adjacent hiddens -> one b32 write of the packed pair
            buf[wr] = __builtin_bit_cast(unsigned int, __builtin_amdgcn_cvt_pkrtz(h0, h1));

            // next step's C-init in the pre-barrier slack (x from registers)
            float xt1 = (u == 0) ? xcur.y : (u == 1) ? xcur.z : (u == 2) ? xcur.w : xnxt.x;
            #pragma unroll
            for (int tau = 0; tau < 2; ++tau)
                #pragma unroll
                for (int r = 0; r < 4; ++r)
                    cq[tau][r] = fmaf(xt1, wih[tau][r], bia[tau][r]);

            __syncthreads();
            // B-frag: pairs quad*4..+3 of batch col = k quad*8..quad*8+7
            uint4 bv = *(const uint4*)&buf[col * 20 + quad * 4];
            bfrag = __builtin_bit_cast(f16x8, bv);
        }
        xcur = xnxt;
    }

    // ---- epilogue: out[b] = sum_j h_j * W_lin[j] + b_lin ----
    float v = fmaf(h0, wl0, h1 * wl1);
    v += __shfl_xor(v, 16);            // combine quads
    v += __shfl_xor(v, 32);
    if (lane < 16) ps[wv * 16 + col] = v;
    __syncthreads();
    if (tid < 16)
        out[base + tid] = b_lin[0] + ps[tid] + ps[16 + tid] + ps[32 + tid] + ps[48 + tid];
}

extern "C" void kernel_launch(void* const* d_in, const int* in_sizes, int n_in,
                              void* d_out, int out_size, void* d_ws, size_t ws_size,
                              hipStream_t stream) {
    const float* x     = (const float*)d_in[0];
    const float* W_ih  = (const float*)d_in[1];
    const float* W_hh  = (const float*)d_in[2];
    const float* b_ih  = (const float*)d_in[3];
    const float* b_hh  = (const float*)d_in[4];
    const float* W_lin = (const float*)d_in[5];
    const float* b_lin = (const float*)d_in[6];
    float* out = (float*)d_out;

    const int B = in_sizes[0] / 512;   // 8192
    dim3 grid(B / 16), block(256);
    lstm_ct4x<<<grid, block, 0, stream>>>(x, W_ih, W_hh, b_ih, b_hh, W_lin, b_lin, out);
}

// Round 15
// 217.600 us; speedup vs baseline: 1.0622x; 1.0622x over previous
//
#include <hip/hip_runtime.h>

// LSTM B=8192, T=512, I=1, H=32; out[b] = h_T . W_lin + b_lin.  All I/O f32.
//
// FINAL (R13 green, restored after R14's x-b128 variant regressed 171->181).
//
// MFMA formulation, 4 waves per 16-batch group (512 blocks x 256 threads),
// custom tiles (zero MFMA duplication), 2 hiddens/lane, fused activations
// with PAIRED rcp.
//
// Wave wv owns hiddens [8wv, 8wv+8). Lane (quad,col) owns j0 = 8wv+2quad+0
// and j1 = j0+1 of batch col. Custom A-tile tau: row m = 4a+r holds W_hh
// gate-row [type r][hidden 8wv+2a+tau] (row-permuting A permutes D rows
// identically), so acc[tau] slots 0..3 = {i,f,g,o} of hidden j0+tau.
// 2 MFMAs/wave-step, no duplication. 2048 waves = 2/SIMD.
//
// Activations (12 trans/lane-step = 10 exp2 + 2 paired rcp — the algebraic
// floor of 5 exp2 + ~1 rcp per hidden-step):
//   e* = 2^(-z*'), a* = 1+e*;  D = aF*aI*aG per hidden
//   paired: r = rcp(D0*D1); 1/D0 = r*D1, 1/D1 = r*D0
//   c' = (c*aI*aG + (1-eG)*aF) / D
//   eC = 2^(-2*L2E*c'); H = aO*(1+eC) paired-rcp; h = (1-eC)/H
// Pre-acts pre-scaled by L2E (2*L2E for the g gate).
//
// Session ledger (dur_us): dot2-VALU 490 -> mfma 1-wave 360 -> 2-wave 297
// -> 4-wave trans-split 215 -> 8-wave custom-tile 190 -> 4-wave custom-tile
// 171 (this). Failed/regressed: 8-wave dup (268), dual-group 1/SIMD (268),
// packed f32x2 acts (post-timing determinism FAIL), x-as-b128 (181).
// Status: chain-limited — wall 801 cyc/step vs busy/SIMD 547; the serial
// barrier->ds_read->MFMA->exp2/rcp-chain->write loop (~800 cyc) IS the
// algorithm's cross-hidden dependency. Busy floor ~117 us; trans at floor.
// NOTE: packed f32x2 (v_pk_*) activation math failed the harness post-timing
// determinism check in R12 — do not reintroduce.

#define L2E 1.4426950408889634f

typedef _Float16 f16x8 __attribute__((ext_vector_type(8)));
typedef float    f32x4 __attribute__((ext_vector_type(4)));

__global__ __launch_bounds__(256, 4) void lstm_ct4r(
    const float* __restrict__ x,      // [B*512]
    const float* __restrict__ W_ih,   // [128]
    const float* __restrict__ W_hh,   // [128*32]
    const float* __restrict__ b_ih,   // [128]
    const float* __restrict__ b_hh,   // [128]
    const float* __restrict__ W_lin,  // [32]
    const float* __restrict__ b_lin,  // [1]
    float* __restrict__ out)          // [B]
{
    __shared__ float xs[512 * 17];                        // x transposed [t][b], stride 17
    __shared__ __align__(16) unsigned int hb[2][16 * 20]; // h half2 buffers, col-stride 20 uints
    __shared__ float ps[64];                              // epilogue partials

    const int tid  = threadIdx.x;
    const int wv   = tid >> 6;         // 0..3: owns hiddens [8wv, 8wv+8)
    const int lane = tid & 63;
    const int col  = lane & 15;        // batch within group
    const int quad = lane >> 4;        // 0..3
    const int base = blockIdx.x * 16;  // global batch base

    // ---- stage x[base..base+15][0..511] into LDS transposed ----
    {
        const float4* xg = (const float4*)(x + (size_t)base * 512);
        #pragma unroll
        for (int it = 0; it < 8; ++it) {
            int idx = it * 256 + tid;          // 0..2047 float4s
            float4 v = xg[idx];
            int b  = idx >> 7;                 // batch 0..15
            int t0 = (idx & 127) * 4;
            xs[(t0 + 0) * 17 + b] = v.x;
            xs[(t0 + 1) * 17 + b] = v.y;
            xs[(t0 + 2) * 17 + b] = v.z;
            xs[(t0 + 3) * 17 + b] = v.w;
        }
    }

    // ---- custom A-tiles: tile tau row m=4a+rt -> W_hh[32*rt + 8wv+2a+tau] ----
    f16x8 wA[2];
    #pragma unroll
    for (int tau = 0; tau < 2; ++tau) {
        const int rt = col & 3;                           // gate type of row col
        const float s = (rt == 2) ? (2.0f * L2E) : L2E;
        const int grow = 32 * rt + 8 * wv + 2 * (col >> 2) + tau;
        #pragma unroll
        for (int j = 0; j < 8; ++j)
            wA[tau][j] = (_Float16)(W_hh[grow * 32 + quad * 8 + j] * s);
    }
    // C-init constants: acc[tau] slot r = gate type r of hidden j0+tau
    const int j0 = 8 * wv + 2 * quad;                     // first owned hidden
    float wih[2][4], bia[2][4];
    #pragma unroll
    for (int tau = 0; tau < 2; ++tau)
        #pragma unroll
        for (int r = 0; r < 4; ++r) {
            const float s = (r == 2) ? (2.0f * L2E) : L2E;
            const int g = 32 * r + j0 + tau;
            wih[tau][r] = W_ih[g] * s;
            bia[tau][r] = (b_ih[g] + b_hh[g]) * s;
        }
    const float wl0 = W_lin[j0], wl1 = W_lin[j0 + 1];

    __syncthreads();

    float c0 = 0.0f, c1 = 0.0f, h0 = 0.0f, h1 = 0.0f;
    f16x8 bfrag = {};                  // h = 0
    f32x4 cq[2];
    {
        float xt = xs[col];            // t = 0
        #pragma unroll
        for (int tau = 0; tau < 2; ++tau)
            #pragma unroll
            for (int r = 0; r < 4; ++r)
                cq[tau][r] = fmaf(xt, wih[tau][r], bia[tau][r]);
    }

    const int wr = col * 20 + 4 * wv + quad;   // h-pair write index (= j0/2 slot)

    #pragma unroll 4
    for (int t = 0; t < 512; ++t) {
        unsigned int* buf = hb[t & 1];

        f32x4 a0 = __builtin_amdgcn_mfma_f32_16x16x32_f16(wA[0], bfrag, cq[0], 0, 0, 0);
        f32x4 a1 = __builtin_amdgcn_mfma_f32_16x16x32_f16(wA[1], bfrag, cq[1], 0, 0, 0);

        float xt1 = xs[((t + 1) & 511) * 17 + col];       // prefetch next x

        // fused activations, hidden j0 (a0) and j0+1 (a1); rcps PAIRED
        float ei0 = __builtin_amdgcn_exp2f(-a0[0]);
        float ef0 = __builtin_amdgcn_exp2f(-a0[1]);
        float eg0 = __builtin_amdgcn_exp2f(-a0[2]);
        float eo0 = __builtin_amdgcn_exp2f(-a0[3]);
        float ei1 = __builtin_amdgcn_exp2f(-a1[0]);
        float ef1 = __builtin_amdgcn_exp2f(-a1[1]);
        float eg1 = __builtin_amdgcn_exp2f(-a1[2]);
        float eo1 = __builtin_amdgcn_exp2f(-a1[3]);
        float aI0 = 1.0f + ei0, aF0 = 1.0f + ef0, aG0 = 1.0f + eg0, aO0 = 1.0f + eo0;
        float aI1 = 1.0f + ei1, aF1 = 1.0f + ef1, aG1 = 1.0f + eg1, aO1 = 1.0f + eo1;
        float tIG0 = aI0 * aG0, tIG1 = aI1 * aG1;
        float num0 = fmaf(c0, tIG0, (1.0f - eg0) * aF0);
        float num1 = fmaf(c1, tIG1, (1.0f - eg1) * aF1);
        float D0 = aF0 * tIG0, D1 = aF1 * tIG1;
        float rD = __builtin_amdgcn_rcpf(D0 * D1);        // paired rcp #1
        c0 = num0 * (rD * D1);
        c1 = num1 * (rD * D0);
        float ec0 = __builtin_amdgcn_exp2f(c0 * (-2.0f * L2E));
        float ec1 = __builtin_amdgcn_exp2f(c1 * (-2.0f * L2E));
        float H0 = aO0 * (1.0f + ec0), H1 = aO1 * (1.0f + ec1);
        float rH = __builtin_amdgcn_rcpf(H0 * H1);        // paired rcp #2
        h0 = (1.0f - ec0) * (rH * H1);
        h1 = (1.0f - ec1) * (rH * H0);

        // adjacent hiddens -> one b32 write of the packed pair
        buf[wr] = __builtin_bit_cast(unsigned int, __builtin_amdgcn_cvt_pkrtz(h0, h1));

        // next step's C-init in the pre-barrier slack
        #pragma unroll
        for (int tau = 0; tau < 2; ++tau)
            #pragma unroll
            for (int r = 0; r < 4; ++r)
                cq[tau][r] = fmaf(xt1, wih[tau][r], bia[tau][r]);

        __syncthreads();
        // B-frag: pairs quad*4..+3 of batch col = k quad*8..quad*8+7
        uint4 bv = *(const uint4*)&buf[col * 20 + quad * 4];
        bfrag = __builtin_bit_cast(f16x8, bv);
    }

    // ---- epilogue: out[b] = sum_j h_j * W_lin[j] + b_lin ----
    float v = fmaf(h0, wl0, h1 * wl1);
    v += __shfl_xor(v, 16);            // combine quads
    v += __shfl_xor(v, 32);
    if (lane < 16) ps[wv * 16 + col] = v;
    __syncthreads();
    if (tid < 16)
        out[base + tid] = b_lin[0] + ps[tid] + ps[16 + tid] + ps[32 + tid] + ps[48 + tid];
}

extern "C" void kernel_launch(void* const* d_in, const int* in_sizes, int n_in,
                              void* d_out, int out_size, void* d_ws, size_t ws_size,
                              hipStream_t stream) {
    const float* x     = (const float*)d_in[0];
    const float* W_ih  = (const float*)d_in[1];
    const float* W_hh  = (const float*)d_in[2];
    const float* b_ih  = (const float*)d_in[3];
    const float* b_hh  = (const float*)d_in[4];
    const float* W_lin = (const float*)d_in[5];
    const float* b_lin = (const float*)d_in[6];
    float* out = (float*)d_out;

    const int B = in_sizes[0] / 512;   // 8192
    dim3 grid(B / 16), block(256);
    lstm_ct4r<<<grid, block, 0, stream>>>(x, W_ih, W_hh, b_ih, b_hh, W_lin, b_lin, out);
}